// Round 3
// baseline (129.570 us; speedup 1.0000x reference)
//
#include <hip/hip_runtime.h>
#include <hip/hip_bf16.h>

// Modulated conv2d (StyleGAN2) on MI355X.
// out[b,o] = rsig[b,o] * conv(s[b,:]*x[b,:], W*SCALE)   (shared weights)
// rsig[b,o] = 1/sqrt(sum_i s[b,i]^2 * wsq[o,i] + 1e-8)
// Conv as implicit GEMM: D[o][p] = sum_k Wb[o][k] * Xcl[p][k].
//
// R3: A (weights) NEVER touches LDS. pack_w emits wAf in MFMA-fragment order
// [o16][k32][lane][8] -> per K-step a wave loads its A-frags as coalesced
// global_load_dwordx4 into registers (ping-pong aP/aQ, prefetch 1 tile ahead,
// static indices only). LDS holds only B (256x64, triple-buffered, XOR
// swizzle). One s_barrier + one counted vmcnt(12) per K-tile. This cuts LDS
// traffic per K-tile/CU from ~176 KB to ~96 KB -> MFMA pipe becomes critical.

typedef __attribute__((ext_vector_type(4))) float f32x4;
typedef __attribute__((ext_vector_type(8))) short bf16x8;

#define NB    16
#define CIN   512
#define COUT  512
#define KTOT  4608           // CIN * 9
#define NPIX  (NB * 32 * 32) // 16384
#define KTILES 72
#define BUFB_ELEM (256 * 64) // one B buffer: 32 KB (bf16 elements)

#define WAITV12() asm volatile("s_waitcnt vmcnt(12)" ::: "memory")
#define WAITV8()  asm volatile("s_waitcnt vmcnt(8)" ::: "memory")
#define FENCE()   asm volatile("" ::: "memory")
#define BAR()     { FENCE(); __builtin_amdgcn_s_barrier(); FENCE(); }

__device__ __forceinline__ void gload_lds16(const void* g, void* l) {
  __builtin_amdgcn_global_load_lds(
      (__attribute__((address_space(1))) void*)(g),
      (__attribute__((address_space(3))) void*)(l), 16, 0, 0);
}

// ---------------- kernel 1: pack weights into MFMA-fragment order + wsq ----
// wAf[((r16*144 + c32)*64 + lane)*8 + j] where o = r16*16 + (lane&15),
// kglob = c32*32 + (lane>>4)*8 + j  (matches mfma_f32_16x16x32_bf16 A layout).
__global__ __launch_bounds__(256) void pack_w_kernel(
    const float* __restrict__ w, __hip_bfloat16* __restrict__ wAf,
    float* __restrict__ wsq) {
  const int idx = blockIdx.x * 256 + threadIdx.x;   // = o*512 + ci
  const int o = idx >> 9, ci = idx & 511;
  const float* wp = w + (size_t)idx * 9;
  const float WSCALE = 0.014731391274719739f;       // 1/sqrt(512*9)
  const int r16 = o >> 4;
  float sum = 0.f;
#pragma unroll
  for (int t = 0; t < 9; ++t) {
    float v = wp[t] * WSCALE;
    sum += v * v;
    const int kg = t * 512 + ci;
    const int c32 = kg >> 5;
    const int ln = (o & 15) | (((kg >> 3) & 3) << 4);
    wAf[(((size_t)(r16 * 144 + c32)) << 9) + (ln << 3) + (kg & 7)] =
        __float2bfloat16(v);
  }
  wsq[idx] = sum;
}

// ---------------- kernel 2: rsig[b][o], one wave per (b,o) ----------------
__global__ __launch_bounds__(256) void calc_rsig_kernel(
    const float* __restrict__ s, const float* __restrict__ wsq,
    float* __restrict__ rsig) {
  const int wid = blockIdx.x * 4 + (threadIdx.x >> 6); // b*512 + o
  const int lane = threadIdx.x & 63;
  const int b = wid >> 9, o = wid & 511;
  const float* sp = s + b * 512;
  const float* wp = wsq + o * 512;
  float sum = 0.f;
#pragma unroll
  for (int i = 0; i < 8; ++i) {
    float sv = sp[lane + i * 64];
    sum += sv * sv * wp[lane + i * 64];
  }
#pragma unroll
  for (int off = 32; off > 0; off >>= 1) sum += __shfl_down(sum, off, 64);
  if (lane == 0) rsig[wid] = 1.0f / sqrtf(sum + 1e-8f);
}

// ---------------- kernel 3: modulate + NCHW->padded channels-last bf16 -----
__global__ __launch_bounds__(256) void modulate_kernel(
    const float* __restrict__ x, const float* __restrict__ s,
    __hip_bfloat16* __restrict__ xpad) {
  const int by = blockIdx.x;            // b*32 + y
  const int b = by >> 5, y = by & 31;
  __shared__ __attribute__((aligned(16))) __hip_bfloat16 tile[32][72];
  const int tid = threadIdx.x;
  const int xc = tid & 31;
  const int cr0 = tid >> 5;             // 0..7
  const float* xrow = x + ((size_t)b * 512 * 32 + y) * 32; // + ci*1024 + xc
  const float* sb = s + b * 512;
  __hip_bfloat16* orow = xpad + (size_t)((b * 34 + y + 1) * 34) * 512;

  for (int ci0 = 0; ci0 < 512; ci0 += 64) {
#pragma unroll
    for (int r = 0; r < 8; ++r) {
      const int cir = r * 8 + cr0;
      const int ci = ci0 + cir;
      float v = xrow[(size_t)ci * 1024 + xc] * sb[ci];
      tile[xc][cir] = __float2bfloat16(v);
    }
    __syncthreads();
    const int xcw = tid >> 3, vec = tid & 7;
    bf16x8 v = *(const bf16x8*)&tile[xcw][vec * 8];
    *(bf16x8*)(orow + (size_t)(xcw + 1) * 512 + ci0 + vec * 8) = v;
    __syncthreads();
  }
}

// ---------------- kernel 4: implicit-GEMM conv, A-in-registers -------------
// Per body kt: stage B(kt+2) [4 gload_lds] | load A(kt+1)->regs [8 dwordx4] |
// ds_read B(kt) frags [8 b128] | 32 MFMA | vmcnt(12) | s_barrier.
// vmcnt(12) = the 12 vmem ops issued THIS body stay outstanding; everything
// older (incl. B(kt+1) staging) has landed. A-reg deps waited by compiler.
#define CONV_BODY(KT, AUSE, ANEXT)                                            \
  {                                                                           \
    const int kt_ = (KT);                                                     \
    const __hip_bfloat16* bufB = lds + (kt_ % 3) * BUFB_ELEM;                 \
    if (kt_ + 2 < KTILES) {                                                   \
      const int kt2 = kt_ + 2;                                                \
      const int tap = kt2 >> 3;                                               \
      const int xoff = (tap + 31 * (tap / 3)) * 512 + ((kt2 & 7) << 6);       \
      __hip_bfloat16* dstb = lds + (kt2 % 3) * BUFB_ELEM;                     \
      _Pragma("unroll")                                                       \
      for (int r = 0; r < 4; ++r)                                             \
        gload_lds16(xpad + (size_t)(gB[r] + xoff),                            \
                    dstb + (size_t)(r * 512 + (wv << 6)) * 8);                \
    }                                                                         \
    if (kt_ + 1 < KTILES) {                                                   \
      _Pragma("unroll")                                                       \
      for (int mi = 0; mi < 4; ++mi)                                          \
        _Pragma("unroll")                                                     \
        for (int kk = 0; kk < 2; ++kk)                                        \
          ANEXT[mi * 2 + kk] = *(const bf16x8*)(wAf +                         \
              (((size_t)((r16b + mi) * 144 + 2 * (kt_ + 1) + kk)) << 9) +     \
              (lane << 3));                                                   \
    }                                                                         \
    bf16x8 bv0[4], bv1[4];                                                    \
    _Pragma("unroll")                                                         \
    for (int ni = 0; ni < 4; ++ni) {                                          \
      const int row = (wc << 6) + (ni << 4) + (lane & 15);                    \
      const int swz = (row & 7) << 4;                                         \
      const int kb = (lane >> 4) << 4;                                        \
      bv0[ni] = *(const bf16x8*)((const char*)bufB + row * 128 +              \
                                 (kb ^ swz));                                 \
      bv1[ni] = *(const bf16x8*)((const char*)bufB + row * 128 +              \
                                 ((64 | kb) ^ swz));                          \
    }                                                                         \
    __builtin_amdgcn_s_setprio(1);                                            \
    _Pragma("unroll")                                                         \
    for (int mi = 0; mi < 4; ++mi)                                            \
      _Pragma("unroll")                                                       \
      for (int ni = 0; ni < 4; ++ni)                                          \
        acc[mi][ni] = __builtin_amdgcn_mfma_f32_16x16x32_bf16(                \
            AUSE[mi * 2 + 0], bv0[ni], acc[mi][ni], 0, 0, 0);                 \
    _Pragma("unroll")                                                         \
    for (int mi = 0; mi < 4; ++mi)                                            \
      _Pragma("unroll")                                                       \
      for (int ni = 0; ni < 4; ++ni)                                          \
        acc[mi][ni] = __builtin_amdgcn_mfma_f32_16x16x32_bf16(                \
            AUSE[mi * 2 + 1], bv1[ni], acc[mi][ni], 0, 0, 0);                 \
    __builtin_amdgcn_s_setprio(0);                                            \
    if (kt_ < KTILES - 2) { WAITV12(); }                                      \
    else if (kt_ == KTILES - 2) { WAITV8(); }                                 \
    BAR();                                                                    \
  }

__global__ __launch_bounds__(512, 2) void conv_gemm_kernel(
    const __hip_bfloat16* __restrict__ wAf,   // fragment-packed [32][144][64][8]
    const __hip_bfloat16* __restrict__ xpad,  // [16][34][34][512]
    const float* __restrict__ rsig,           // [16][512]
    float* __restrict__ out) {                // [16][512][32][32]
  extern __shared__ __attribute__((aligned(16))) __hip_bfloat16 lds[];

  const int tid = threadIdx.x;
  const int wv = tid >> 6, lane = tid & 63;
  // XCD swizzle: 256 blocks, 8 XCDs -> each XCD gets 32 consecutive ranks
  // (one cout-panel per XCD -> 1.18 MB A working set, L2-resident).
  const int rank = (blockIdx.x & 7) * 32 + (blockIdx.x >> 3);
  const int bo0 = (rank >> 6) << 7;   // cout block (128)
  const int bp0 = (rank & 63) << 8;   // pixel block (256; 256 | 1024)
  const int wr = wv >> 2, wc = wv & 3;   // wave grid 2(M) x 4(N)
  const int r16b = (bo0 >> 4) + wr * 4;

  // B staging source offsets (pre-swizzled chunk within row; rule 21).
  int gB[4];
#pragma unroll
  for (int r = 0; r < 4; ++r) {
    const int c = r * 512 + tid, row = c >> 3, sc = (c & 7) ^ (row & 7);
    const int p = bp0 + row, b = p >> 10, rem = p & 1023, y = rem >> 5,
              xx = rem & 31;
    gB[r] = ((b * 34 + y) * 34 + xx) * 512 + sc * 8;
  }

  f32x4 acc[4][4];
#pragma unroll
  for (int mi = 0; mi < 4; ++mi)
#pragma unroll
    for (int ni = 0; ni < 4; ++ni) acc[mi][ni] = f32x4{0.f, 0.f, 0.f, 0.f};

  bf16x8 aP[8], aQ[8];

  // Prologue (fences pin issue order: B0 | A0 | B1 -> vmcnt(12) proves B0).
#pragma unroll
  for (int r = 0; r < 4; ++r)
    gload_lds16(xpad + (size_t)gB[r], lds + (size_t)(r * 512 + (wv << 6)) * 8);
  FENCE();
#pragma unroll
  for (int mi = 0; mi < 4; ++mi)
#pragma unroll
    for (int kk = 0; kk < 2; ++kk)
      aP[mi * 2 + kk] = *(const bf16x8*)(
          wAf + (((size_t)((r16b + mi) * 144 + kk)) << 9) + (lane << 3));
  FENCE();
#pragma unroll
  for (int r = 0; r < 4; ++r)
    gload_lds16(xpad + (size_t)(gB[r] + 64),
                lds + BUFB_ELEM + (size_t)(r * 512 + (wv << 6)) * 8);
  WAITV12();
  BAR();

#pragma unroll 1
  for (int kt = 0; kt < KTILES; kt += 2) {
    CONV_BODY(kt, aP, aQ);
    CONV_BODY(kt + 1, aQ, aP);
  }

  // Epilogue: D[o][p] * rsig[b][o]. C/D: col(=p)=lane&15, row(=o)=(lane>>4)*4+r
  const int bimg = bp0 >> 10;
#pragma unroll
  for (int mi = 0; mi < 4; ++mi) {
    const int o = bo0 + (wr << 6) + (mi << 4) + ((lane >> 4) << 2);
    const f32x4 rs = *(const f32x4*)(rsig + (bimg << 9) + o);
#pragma unroll
    for (int ni = 0; ni < 4; ++ni) {
      const int p = bp0 + (wc << 6) + (ni << 4) + (lane & 15);
      const int prem = p & 1023;
#pragma unroll
      for (int r = 0; r < 4; ++r)
        out[((size_t)(bimg << 9) + o + r) * 1024 + prem] =
            acc[mi][ni][r] * rs[r];
    }
  }
}

extern "C" void kernel_launch(void* const* d_in, const int* in_sizes, int n_in,
                              void* d_out, int out_size, void* d_ws,
                              size_t ws_size, hipStream_t stream) {
  const float* x = (const float*)d_in[0];   // [16,512,32,32]
  const float* s = (const float*)d_in[1];   // [16,512]
  const float* w = (const float*)d_in[2];   // [512,512,3,3]
  float* out = (float*)d_out;               // [16,512,32,32] f32

  char* ws = (char*)d_ws;
  const size_t xpad_bytes = (size_t)NB * 34 * 34 * 512 * 2;  // 18,939,904
  const size_t wA_bytes = (size_t)COUT * KTOT * 2;           //  4,718,592
  const size_t wsq_bytes = (size_t)COUT * CIN * 4;           //  1,048,576
  __hip_bfloat16* xpad = (__hip_bfloat16*)ws;
  __hip_bfloat16* wAf = (__hip_bfloat16*)(ws + xpad_bytes);
  float* wsq = (float*)(ws + xpad_bytes + wA_bytes);
  float* rsig = (float*)(ws + xpad_bytes + wA_bytes + wsq_bytes);

  const int lds_bytes = 3 * BUFB_ELEM * 2;   // 98304 B = 96 KiB
  hipFuncSetAttribute((const void*)conv_gemm_kernel,
                      hipFuncAttributeMaxDynamicSharedMemorySize, lds_bytes);

  hipMemsetAsync(xpad, 0, xpad_bytes, stream);  // zero halo (capturable)
  pack_w_kernel<<<(COUT * CIN) / 256, 256, 0, stream>>>(w, wAf, wsq);
  modulate_kernel<<<NB * 32, 256, 0, stream>>>(x, s, xpad);
  calc_rsig_kernel<<<(NB * COUT) / 4, 256, 0, stream>>>(s, wsq, rsig);
  conv_gemm_kernel<<<256, 512, lds_bytes, stream>>>(wAf, xpad, rsig, out);
}

// Round 4
// 114.148 us; speedup vs baseline: 1.1351x; 1.1351x over previous
//
#include <hip/hip_runtime.h>
#include <hip/hip_bf16.h>

// Modulated conv2d (StyleGAN2) on MI355X.
// out[b,o] = rsig[b,o] * conv(s[b,:]*x[b,:], W*SCALE)   (shared weights)
// rsig[b,o] = 1/sqrt(sum_i s[b,i]^2 * wsq[o,i] + 1e-8)
// Conv as implicit GEMM: D[o][p] = sum_k Wb[o][k] * Xcl[p][k].
//
// R4: back to A-via-global_load_lds (R3's per-wave A global loads caused 300MB
// beyond-L2 refetch). Loop rebuilt as m201-style 4-phase fine interleave:
// each K64-tile = 4 phases of {ds_reads (8/4/4/0) | 2 staging issues | BAR |
// lgkmcnt(0)+sched_barrier | setprio(1) 8 MFMA setprio(0) | BAR}; B frags held
// in regs across phases (reads stay at the 16-b128 minimum). Triple-buffered
// LDS (144 KiB), prefetch distance 2, counted vmcnt(6) once per K-tile.

typedef __attribute__((ext_vector_type(4))) float f32x4;
typedef __attribute__((ext_vector_type(8))) short bf16x8;

#define NB    16
#define CIN   512
#define COUT  512
#define KTOT  4608           // CIN * 9
#define NPIX  (NB * 32 * 32) // 16384
#define KTILES 72
#define BUFELEM 24576        // (128*64 A + 256*64 B) bf16 elems per buffer

#define WAITV6() asm volatile("s_waitcnt vmcnt(6)" ::: "memory")
#define WAITV0() asm volatile("s_waitcnt vmcnt(0)" ::: "memory")
#define LGKM0()  asm volatile("s_waitcnt lgkmcnt(0)" ::: "memory")
#define SCHED0() __builtin_amdgcn_sched_barrier(0)
#define FENCE()  asm volatile("" ::: "memory")
#define BAR()    { FENCE(); __builtin_amdgcn_s_barrier(); FENCE(); }

__device__ __forceinline__ void gload_lds16(const void* g, void* l) {
  __builtin_amdgcn_global_load_lds(
      (__attribute__((address_space(1))) void*)(g),
      (__attribute__((address_space(3))) void*)(l), 16, 0, 0);
}

// ---------------- kernel 1: pack weights (bf16, [o][tap*512+ci]) + wsq -----
__global__ __launch_bounds__(256) void pack_w_kernel(
    const float* __restrict__ w, __hip_bfloat16* __restrict__ wB,
    float* __restrict__ wsq) {
  const int idx = blockIdx.x * 256 + threadIdx.x;   // = o*512 + ci
  const int o = idx >> 9, ci = idx & 511;
  const float* wp = w + (size_t)idx * 9;
  const float WSCALE = 0.014731391274719739f;       // 1/sqrt(512*9)
  float sum = 0.f;
#pragma unroll
  for (int t = 0; t < 9; ++t) {
    float v = wp[t] * WSCALE;
    sum += v * v;
    wB[(size_t)o * KTOT + t * 512 + ci] = __float2bfloat16(v);
  }
  wsq[idx] = sum;
}

// ---------------- kernel 2: rsig[b][o], one wave per (b,o) ----------------
__global__ __launch_bounds__(256) void calc_rsig_kernel(
    const float* __restrict__ s, const float* __restrict__ wsq,
    float* __restrict__ rsig) {
  const int wid = blockIdx.x * 4 + (threadIdx.x >> 6); // b*512 + o
  const int lane = threadIdx.x & 63;
  const int b = wid >> 9, o = wid & 511;
  const float* sp = s + b * 512;
  const float* wp = wsq + o * 512;
  float sum = 0.f;
#pragma unroll
  for (int i = 0; i < 8; ++i) {
    float sv = sp[lane + i * 64];
    sum += sv * sv * wp[lane + i * 64];
  }
#pragma unroll
  for (int off = 32; off > 0; off >>= 1) sum += __shfl_down(sum, off, 64);
  if (lane == 0) rsig[wid] = 1.0f / sqrtf(sum + 1e-8f);
}

// ---------------- kernel 3: modulate + NCHW->padded channels-last bf16 -----
__global__ __launch_bounds__(256) void modulate_kernel(
    const float* __restrict__ x, const float* __restrict__ s,
    __hip_bfloat16* __restrict__ xpad) {
  const int by = blockIdx.x;            // b*32 + y
  const int b = by >> 5, y = by & 31;
  __shared__ __attribute__((aligned(16))) __hip_bfloat16 tile[32][72];
  const int tid = threadIdx.x;
  const int xc = tid & 31;
  const int cr0 = tid >> 5;             // 0..7
  const float* xrow = x + ((size_t)b * 512 * 32 + y) * 32; // + ci*1024 + xc
  const float* sb = s + b * 512;
  __hip_bfloat16* orow = xpad + (size_t)((b * 34 + y + 1) * 34) * 512;

  for (int ci0 = 0; ci0 < 512; ci0 += 64) {
#pragma unroll
    for (int r = 0; r < 8; ++r) {
      const int cir = r * 8 + cr0;
      const int ci = ci0 + cir;
      float v = xrow[(size_t)ci * 1024 + xc] * sb[ci];
      tile[xc][cir] = __float2bfloat16(v);
    }
    __syncthreads();
    const int xcw = tid >> 3, vec = tid & 7;
    bf16x8 v = *(const bf16x8*)&tile[xcw][vec * 8];
    *(bf16x8*)(orow + (size_t)(xcw + 1) * 512 + ci0 + vec * 8) = v;
    __syncthreads();
  }
}

// ---------------- kernel 4: implicit-GEMM conv, 4-phase fine interleave ----
// LDS buffer i (i=0..2): A = 128x64 rows at lds+i*BUFELEM, B = 256x64 at +8192.
// Row-major 128 B/row, XOR swizzle byte ^= ((row&7)<<4) on staging source and
// ds_read address (rule 21; 0 bank conflicts measured R1/R2).
__global__ __launch_bounds__(512, 2) void conv_gemm_kernel(
    const __hip_bfloat16* __restrict__ wB,    // [512][4608]
    const __hip_bfloat16* __restrict__ xpad,  // [16][34][34][512]
    const float* __restrict__ rsig,           // [16][512]
    float* __restrict__ out) {                // [16][512][32][32]
  extern __shared__ __attribute__((aligned(16))) __hip_bfloat16 lds[];

  const int tid = threadIdx.x;
  const int wv = tid >> 6, lane = tid & 63;
  const int bo0 = blockIdx.y << 7;   // cout block (128)
  const int bp0 = blockIdx.x << 8;   // pixel block (256; 256 | 1024 per image)
  const int wr = wv >> 2, wc = wv & 3;   // wave grid 2(M) x 4(N)

  // Staging source offsets (pre-swizzled chunk within row; rule 21).
  int gA[2];   // element offset in wB; add kt*64 per tile
#pragma unroll
  for (int r = 0; r < 2; ++r) {
    const int c = r * 512 + tid, row = c >> 3, sc = (c & 7) ^ (row & 7);
    gA[r] = (bo0 + row) * KTOT + sc * 8;
  }
  int gB[4];   // element offset in xpad; add tapoff*512 + ci0 per tile
#pragma unroll
  for (int r = 0; r < 4; ++r) {
    const int c = r * 512 + tid, row = c >> 3, sc = (c & 7) ^ (row & 7);
    const int p = bp0 + row, b = p >> 10, rem = p & 1023, y = rem >> 5,
              xx = rem & 31;
    gB[r] = ((b * 34 + y) * 34 + xx) * 512 + sc * 8;
  }

  auto stageA = [&](int kt2, int r) {
    __hip_bfloat16* dst = lds + (kt2 % 3) * BUFELEM + (size_t)(r * 512 + (wv << 6)) * 8;
    gload_lds16(wB + (size_t)(gA[r] + (kt2 << 6)), dst);
  };
  auto stageB = [&](int kt2, int r, int xoff) {
    __hip_bfloat16* dst = lds + (kt2 % 3) * BUFELEM + 8192 + (size_t)(r * 512 + (wv << 6)) * 8;
    gload_lds16(xpad + (size_t)(gB[r] + xoff), dst);
  };

  f32x4 acc[4][4];
#pragma unroll
  for (int mi = 0; mi < 4; ++mi)
#pragma unroll
    for (int ni = 0; ni < 4; ++ni) acc[mi][ni] = f32x4{0.f, 0.f, 0.f, 0.f};

  // Prologue: fully stage tiles 0 and 1 (6 vmem ops each).
  stageA(0, 0); stageA(0, 1);
  stageB(0, 0, 0); stageB(0, 1, 0); stageB(0, 2, 0); stageB(0, 3, 0);
  stageA(1, 0); stageA(1, 1);
  stageB(1, 0, 64); stageB(1, 1, 64); stageB(1, 2, 64); stageB(1, 3, 64);
  WAITV6();      // tile 0's 6 oldest done; tile 1's 6 still in flight
  BAR();

#pragma unroll 1
  for (int kt = 0; kt < KTILES; ++kt) {
    const __hip_bfloat16* bufA = lds + (kt % 3) * BUFELEM;
    const __hip_bfloat16* bufB = bufA + 8192;
    const int kt2 = kt + 2;
    const bool pf = kt2 < KTILES;
    int xoff = 0;
    if (pf) {
      const int tap = kt2 >> 3;
      xoff = (tap + 31 * (tap / 3)) * 512 + ((kt2 & 7) << 6); // tapoff*512+ci0
    }

    bf16x8 af[4][2], bv[4][2];
    const int kbase = (lane >> 4) << 4;   // 0..48 within a 64B k-half

    // ---------- phase 0: read A[0:2],B[0:2]; stage A; MFMA {0,1}x{0,1} ----
#pragma unroll
    for (int mi = 0; mi < 2; ++mi) {
      const int row = (wr << 6) + (mi << 4) + (lane & 15);
      const int swz = (row & 7) << 4;
      af[mi][0] = *(const bf16x8*)((const char*)bufA + row * 128 + (kbase ^ swz));
      af[mi][1] = *(const bf16x8*)((const char*)bufA + row * 128 + ((64 | kbase) ^ swz));
    }
#pragma unroll
    for (int ni = 0; ni < 2; ++ni) {
      const int row = (wc << 6) + (ni << 4) + (lane & 15);
      const int swz = (row & 7) << 4;
      bv[ni][0] = *(const bf16x8*)((const char*)bufB + row * 128 + (kbase ^ swz));
      bv[ni][1] = *(const bf16x8*)((const char*)bufB + row * 128 + ((64 | kbase) ^ swz));
    }
    if (pf) { stageA(kt2, 0); stageA(kt2, 1); }
    BAR(); LGKM0(); SCHED0();
    __builtin_amdgcn_s_setprio(1);
#pragma unroll
    for (int mi = 0; mi < 2; ++mi)
#pragma unroll
      for (int ni = 0; ni < 2; ++ni)
#pragma unroll
        for (int kk = 0; kk < 2; ++kk)
          acc[mi][ni] = __builtin_amdgcn_mfma_f32_16x16x32_bf16(
              af[mi][kk], bv[ni][kk], acc[mi][ni], 0, 0, 0);
    __builtin_amdgcn_s_setprio(0);
    BAR();

    // ---------- phase 1: read B[2:4]; stage B0,B1; MFMA {0,1}x{2,3} -------
#pragma unroll
    for (int ni = 2; ni < 4; ++ni) {
      const int row = (wc << 6) + (ni << 4) + (lane & 15);
      const int swz = (row & 7) << 4;
      bv[ni][0] = *(const bf16x8*)((const char*)bufB + row * 128 + (kbase ^ swz));
      bv[ni][1] = *(const bf16x8*)((const char*)bufB + row * 128 + ((64 | kbase) ^ swz));
    }
    if (pf) { stageB(kt2, 0, xoff); stageB(kt2, 1, xoff); }
    BAR(); LGKM0(); SCHED0();
    __builtin_amdgcn_s_setprio(1);
#pragma unroll
    for (int mi = 0; mi < 2; ++mi)
#pragma unroll
      for (int ni = 2; ni < 4; ++ni)
#pragma unroll
        for (int kk = 0; kk < 2; ++kk)
          acc[mi][ni] = __builtin_amdgcn_mfma_f32_16x16x32_bf16(
              af[mi][kk], bv[ni][kk], acc[mi][ni], 0, 0, 0);
    __builtin_amdgcn_s_setprio(0);
    BAR();

    // ---------- phase 2: read A[2:4]; stage B2,B3; MFMA {2,3}x{2,3} -------
#pragma unroll
    for (int mi = 2; mi < 4; ++mi) {
      const int row = (wr << 6) + (mi << 4) + (lane & 15);
      const int swz = (row & 7) << 4;
      af[mi][0] = *(const bf16x8*)((const char*)bufA + row * 128 + (kbase ^ swz));
      af[mi][1] = *(const bf16x8*)((const char*)bufA + row * 128 + ((64 | kbase) ^ swz));
    }
    if (pf) { stageB(kt2, 2, xoff); stageB(kt2, 3, xoff); }
    BAR(); LGKM0(); SCHED0();
    __builtin_amdgcn_s_setprio(1);
#pragma unroll
    for (int mi = 2; mi < 4; ++mi)
#pragma unroll
      for (int ni = 2; ni < 4; ++ni)
#pragma unroll
        for (int kk = 0; kk < 2; ++kk)
          acc[mi][ni] = __builtin_amdgcn_mfma_f32_16x16x32_bf16(
              af[mi][kk], bv[ni][kk], acc[mi][ni], 0, 0, 0);
    __builtin_amdgcn_s_setprio(0);
    BAR();

    // ---------- phase 3: MFMA {2,3}x{0,1}; counted vmcnt; close tile ------
    __builtin_amdgcn_s_setprio(1);
#pragma unroll
    for (int mi = 2; mi < 4; ++mi)
#pragma unroll
      for (int ni = 0; ni < 2; ++ni)
#pragma unroll
        for (int kk = 0; kk < 2; ++kk)
          acc[mi][ni] = __builtin_amdgcn_mfma_f32_16x16x32_bf16(
              af[mi][kk], bv[ni][kk], acc[mi][ni], 0, 0, 0);
    __builtin_amdgcn_s_setprio(0);
    if (kt < KTILES - 2) { WAITV6(); } else if (kt == KTILES - 2) { WAITV0(); }
    BAR();
  }

  // Epilogue: D[o][p] * rsig[b][o]. C/D: col(=p)=lane&15, row(=o)=(lane>>4)*4+r
  const int bimg = bp0 >> 10;
#pragma unroll
  for (int mi = 0; mi < 4; ++mi) {
    const int o = bo0 + (wr << 6) + (mi << 4) + ((lane >> 4) << 2);
    const f32x4 rs = *(const f32x4*)(rsig + (bimg << 9) + o);
#pragma unroll
    for (int ni = 0; ni < 4; ++ni) {
      const int p = bp0 + (wc << 6) + (ni << 4) + (lane & 15);
      const int prem = p & 1023;
#pragma unroll
      for (int r = 0; r < 4; ++r)
        out[((size_t)(bimg << 9) + o + r) * 1024 + prem] =
            acc[mi][ni][r] * rs[r];
    }
  }
}

extern "C" void kernel_launch(void* const* d_in, const int* in_sizes, int n_in,
                              void* d_out, int out_size, void* d_ws,
                              size_t ws_size, hipStream_t stream) {
  const float* x = (const float*)d_in[0];   // [16,512,32,32]
  const float* s = (const float*)d_in[1];   // [16,512]
  const float* w = (const float*)d_in[2];   // [512,512,3,3]
  float* out = (float*)d_out;               // [16,512,32,32] f32

  char* ws = (char*)d_ws;
  const size_t xpad_bytes = (size_t)NB * 34 * 34 * 512 * 2;  // 18,939,904
  const size_t wB_bytes = (size_t)COUT * KTOT * 2;           //  4,718,592
  const size_t wsq_bytes = (size_t)COUT * CIN * 4;           //  1,048,576
  __hip_bfloat16* xpad = (__hip_bfloat16*)ws;
  __hip_bfloat16* wB = (__hip_bfloat16*)(ws + xpad_bytes);
  float* wsq = (float*)(ws + xpad_bytes + wB_bytes);
  float* rsig = (float*)(ws + xpad_bytes + wB_bytes + wsq_bytes);

  const int lds_bytes = 3 * BUFELEM * 2;   // 147456 B = 144 KiB
  hipFuncSetAttribute((const void*)conv_gemm_kernel,
                      hipFuncAttributeMaxDynamicSharedMemorySize, lds_bytes);

  hipMemsetAsync(xpad, 0, xpad_bytes, stream);  // zero halo (capturable)
  pack_w_kernel<<<(COUT * CIN) / 256, 256, 0, stream>>>(w, wB, wsq);
  modulate_kernel<<<NB * 32, 256, 0, stream>>>(x, s, xpad);
  calc_rsig_kernel<<<(NB * COUT) / 4, 256, 0, stream>>>(s, wsq, rsig);
  conv_gemm_kernel<<<dim3(NPIX / 256, COUT / 128), 512, lds_bytes, stream>>>(
      wB, xpad, rsig, out);
}